// Round 1
// baseline (9161.028 us; speedup 1.0000x reference)
//
#include <hip/hip_runtime.h>
#include <hip/hip_bf16.h>

#define Dh 2048
#define Bh 4
#define Sh 2048
#define NROW 8192          // B*S
#define HALF 1024
#define INV_SQRT_D 0.022097086912079608f
#define LNEPS 1e-5f

typedef __hip_bfloat16 bf16;

__device__ inline float cvtf(float v) { return v; }
__device__ inline float cvtf(bf16 v) { return __bfloat162float(v); }

__device__ inline float warp_sum(float x) {
#pragma unroll
  for (int o = 32; o > 0; o >>= 1) x += __shfl_down(x, o);
  return x;
}
__device__ inline float warp_max(float x) {
#pragma unroll
  for (int o = 32; o > 0; o >>= 1) x = fmaxf(x, __shfl_down(x, o));
  return x;
}
// 256-thread block reductions (4 waves). Trailing __syncthreads so sm4 is reusable.
__device__ inline float block_sum(float x, float* sm4) {
  x = warp_sum(x);
  int w = threadIdx.x >> 6;
  if ((threadIdx.x & 63) == 0) sm4[w] = x;
  __syncthreads();
  float r = sm4[0] + sm4[1] + sm4[2] + sm4[3];
  __syncthreads();
  return r;
}
__device__ inline float block_max(float x, float* sm4) {
  x = warp_max(x);
  int w = threadIdx.x >> 6;
  if ((threadIdx.x & 63) == 0) sm4[w] = x;
  __syncthreads();
  float r = fmaxf(fmaxf(sm4[0], sm4[1]), fmaxf(sm4[2], sm4[3]));
  __syncthreads();
  return r;
}

// ---------------------------------------------------------------------------
// Generic tiled GEMM: C[M,N] = A[M,K] @ B^T (modes 0,1,2,4: B is [N,K]) or
// A[M,K] @ B (mode 3: B is [K,N]). f32 accumulate, 64x64x16 tiles,
// 256 threads, 4x4 outputs per thread.
// MODE 0: C f32 = acc                                  (prc)
// MODE 1: C bf16 = silu(acc + mu_b[z][c]) * gating[z][b][c]   (qkv)
// MODE 2: C f32 = acc * INV_SQRT_D, skip blocks above causal diagonal (QK^T)
// MODE 3: C bf16 = acc, k-loop bounded at row-tile end  (PV)
// MODE 4: C f32 = x + gating_o[b][c] * silu(acc + mu_b3[c])   (o-proj + resid)
// ---------------------------------------------------------------------------
template <typename TA, typename TB, int MODE>
__global__ __launch_bounds__(256) void gemm_k(
    const TA* __restrict__ Aall, const TB* __restrict__ Ball, void* __restrict__ Call,
    int M, int N, int K, long sAz, long sBz, long sCz,
    const float* __restrict__ e0, const float* __restrict__ e1,
    const float* __restrict__ e2) {
  int bm0 = blockIdx.x * 64;
  int bn0 = blockIdx.y * 64;
  if (MODE == 2 && bn0 > bm0 + 63) return;  // fully above diagonal: never read
  int z = blockIdx.z;
  const TA* A = Aall + (long)z * sAz;
  const TB* Bm = Ball + (long)z * sBz;

  __shared__ float As[16][65];
  __shared__ float Bs[16][65];
  int tid = threadIdx.x;
  int tx = tid & 15, ty = tid >> 4;
  float acc[4][4] = {};

  int kmax = (MODE == 3) ? (bm0 + 64) : K;  // causal PV: probs zero beyond row

  for (int k0 = 0; k0 < kmax; k0 += 16) {
#pragma unroll
    for (int i = 0; i < 4; ++i) {
      int idx = tid + i * 256;
      int m = idx >> 4, kk = idx & 15;
      As[kk][m] = cvtf(A[(long)(bm0 + m) * K + (k0 + kk)]);
    }
#pragma unroll
    for (int i = 0; i < 4; ++i) {
      int idx = tid + i * 256;
      if (MODE == 3) {
        int kk = idx >> 6, n = idx & 63;
        Bs[kk][n] = cvtf(Bm[(long)(k0 + kk) * N + (bn0 + n)]);
      } else {
        int n = idx >> 4, kk = idx & 15;
        Bs[kk][n] = cvtf(Bm[(long)(bn0 + n) * K + (k0 + kk)]);
      }
    }
    __syncthreads();
#pragma unroll
    for (int kk = 0; kk < 16; ++kk) {
      float ra[4], rb[4];
#pragma unroll
      for (int i = 0; i < 4; ++i) ra[i] = As[kk][ty * 4 + i];
#pragma unroll
      for (int j = 0; j < 4; ++j) rb[j] = Bs[kk][tx * 4 + j];
#pragma unroll
      for (int i = 0; i < 4; ++i)
#pragma unroll
        for (int j = 0; j < 4; ++j) acc[i][j] = fmaf(ra[i], rb[j], acc[i][j]);
    }
    __syncthreads();
  }

#pragma unroll
  for (int i = 0; i < 4; ++i) {
    int gr = bm0 + ty * 4 + i;
#pragma unroll
    for (int j = 0; j < 4; ++j) {
      int gc = bn0 + tx * 4 + j;
      float a = acc[i][j];
      if (MODE == 0) {
        float* C = (float*)Call + (long)z * sCz;
        C[(long)gr * N + gc] = a;
      } else if (MODE == 1) {
        float val = a + e0[z * Dh + gc];
        float sil = val / (1.f + __expf(-val));
        int bb = gr >> 11;  // row / S
        float g = e1[(z * Bh + bb) * Dh + gc];
        bf16* C = (bf16*)Call + (long)z * sCz;
        C[(long)gr * N + gc] = __float2bfloat16(sil * g);
      } else if (MODE == 2) {
        float* C = (float*)Call + (long)z * sCz;
        C[(long)gr * N + gc] = a * INV_SQRT_D;
      } else if (MODE == 3) {
        bf16* C = (bf16*)Call + (long)z * sCz;
        C[(long)gr * N + gc] = __float2bfloat16(a);
      } else {
        float val = a + e0[gc];
        float sil = val / (1.f + __expf(-val));
        int bb = gr >> 11;
        float* C = (float*)Call;
        C[(long)gr * N + gc] = e2[(long)gr * N + gc] + e1[bb * Dh + gc] * sil;
      }
    }
  }
}

// LN over D per (b,s) row of x -> bf16
__global__ __launch_bounds__(256) void ln1_kernel(const float* __restrict__ x,
    const float* __restrict__ g, const float* __restrict__ b, bf16* __restrict__ out) {
  __shared__ float sm4[4];
  long r = blockIdx.x;
  const float* row = x + r * Dh;
  float v[8];
  float s = 0.f, s2 = 0.f;
#pragma unroll
  for (int c = 0; c < 8; ++c) {
    float t = row[threadIdx.x + c * 256];
    v[c] = t; s += t; s2 += t * t;
  }
  s = block_sum(s, sm4);
  s2 = block_sum(s2, sm4);
  float mean = s * (1.f / Dh);
  float rstd = rsqrtf(s2 * (1.f / Dh) - mean * mean + LNEPS);
#pragma unroll
  for (int c = 0; c < 8; ++c) {
    int o = threadIdx.x + c * 256;
    out[r * Dh + o] = __float2bfloat16((v[c] - mean) * rstd * g[o] + b[o]);
  }
}

// outbd[b*D+d] += (1/S) * sum over an s-chunk of in[b,s,d]  (bf16 input)
__global__ __launch_bounds__(256) void meanrow_kernel(const bf16* __restrict__ in,
                                                      float* __restrict__ outbd) {
  int gid = blockIdx.x * 256 + threadIdx.x;  // (b,d) in [0, 8192)
  int s0 = blockIdx.y * 128;
  long base = ((long)(gid >> 11) * Sh + s0) * Dh + (gid & 2047);
  float s = 0.f;
  for (int t = 0; t < 128; ++t) s += __bfloat162float(in[base + (long)t * Dh]);
  atomicAdd(&outbd[gid], s * (1.f / Sh));
}

// Per (n,i): LN prc row over o, add proto_w; n<3: dot with ctx[b] -> routing;
// n==3: store proto_state[3] row for the post-attention routing.
__global__ __launch_bounds__(256) void route_kernel(
    const float* __restrict__ prc, const float* __restrict__ proto_w,
    const float* __restrict__ pln_g, const float* __restrict__ pln_b,
    const float* __restrict__ gate, const float* __restrict__ ctx,
    float* __restrict__ routing, float* __restrict__ ps3) {
  __shared__ float sm4[4];
  int i = blockIdx.x, n = blockIdx.y;
  long rb = ((long)n * Dh + i) * Dh;
  float v[8];
  float s = 0.f, s2 = 0.f;
#pragma unroll
  for (int c = 0; c < 8; ++c) {
    float t = prc[rb + threadIdx.x + c * 256];
    v[c] = t; s += t; s2 += t * t;
  }
  s = block_sum(s, sm4);
  s2 = block_sum(s2, sm4);
  float mean = s * (1.f / Dh);
  float rstd = rsqrtf(s2 * (1.f / Dh) - mean * mean + LNEPS);
  if (n == 3) {
#pragma unroll
    for (int c = 0; c < 8; ++c) {
      int o = threadIdx.x + c * 256;
      float ps = proto_w[rb + o] + (v[c] - mean) * rstd * pln_g[3 * Dh + o] + pln_b[3 * Dh + o];
      ps3[(long)i * Dh + o] = ps;
    }
  } else {
    float acc[4] = {0.f, 0.f, 0.f, 0.f};
#pragma unroll
    for (int c = 0; c < 8; ++c) {
      int o = threadIdx.x + c * 256;
      float ps = proto_w[rb + o] + (v[c] - mean) * rstd * pln_g[n * Dh + o] + pln_b[n * Dh + o];
#pragma unroll
      for (int b = 0; b < 4; ++b) acc[b] += ps * ctx[b * Dh + o];
    }
    for (int b = 0; b < 4; ++b) {
      float r = block_sum(acc[b], sm4);
      if (threadIdx.x == 0)
        routing[(n * 4 + b) * Dh + i] = r * INV_SQRT_D + gate[n * Dh + i];
    }
  }
}

// match_o[b][i] from stored proto_state[3]
__global__ __launch_bounds__(256) void route_o_kernel(
    const float* __restrict__ ps3, const float* __restrict__ ctxo,
    const float* __restrict__ gate, float* __restrict__ routing) {
  __shared__ float sm4[4];
  int i = blockIdx.x;
  float acc[4] = {0.f, 0.f, 0.f, 0.f};
#pragma unroll
  for (int c = 0; c < 8; ++c) {
    int o = threadIdx.x + c * 256;
    float p = ps3[(long)i * Dh + o];
#pragma unroll
    for (int b = 0; b < 4; ++b) acc[b] += p * ctxo[b * Dh + o];
  }
  for (int b = 0; b < 4; ++b) {
    float r = block_sum(acc[b], sm4);
    if (threadIdx.x == 0)
      routing[(12 + b) * Dh + i] = r * INV_SQRT_D + gate[3 * Dh + i];
  }
}

// gating = routing / (max|routing| + 1e-9), per row of length D
__global__ __launch_bounds__(256) void masnorm_kernel(const float* __restrict__ rin,
                                                      float* __restrict__ gout) {
  __shared__ float sm4[4];
  long r = blockIdx.x;
  float m = 0.f;
#pragma unroll
  for (int c = 0; c < 8; ++c)
    m = fmaxf(m, fabsf(rin[r * Dh + threadIdx.x + c * 256]));
  m = block_max(m, sm4);
  float inv = 1.f / (m + 1e-9f);
#pragma unroll
  for (int c = 0; c < 8; ++c) {
    int o = threadIdx.x + c * 256;
    gout[r * Dh + o] = rin[r * Dh + o] * inv;
  }
}

__global__ __launch_bounds__(256) void rope_table_kernel(float* __restrict__ cosT,
                                                         float* __restrict__ sinT) {
  int idx = blockIdx.x * 256 + threadIdx.x;  // [S * HALF]
  int t = idx >> 10, f = idx & 1023;
  float inv_freq = expf(-(float)f * (9.210340371976184f / 1024.f));  // ln(10000)/1024
  float ang = (float)t * inv_freq;
  cosT[idx] = cosf(ang);
  sinT[idx] = sinf(ang);
}

// In-place RoPE on q and k (bf16), full hidden dim, rotate_half convention
__global__ __launch_bounds__(256) void rope_kernel(bf16* __restrict__ q, bf16* __restrict__ k,
    const int* __restrict__ pos, const float* __restrict__ cosT,
    const float* __restrict__ sinT) {
  long r = blockIdx.x;               // b*S + s
  int s = (int)(r & (Sh - 1));
  int p = pos[s];
#pragma unroll
  for (int c = 0; c < 4; ++c) {
    int t = threadIdx.x + c * 256;   // 0..1023
    float cv = cosT[(long)p * HALF + t];
    float sv = sinT[(long)p * HALF + t];
    long i1 = r * Dh + t, i2 = i1 + HALF;
    float q1 = __bfloat162float(q[i1]), q2 = __bfloat162float(q[i2]);
    q[i1] = __float2bfloat16(q1 * cv - q2 * sv);
    q[i2] = __float2bfloat16(q2 * cv + q1 * sv);
    float k1 = __bfloat162float(k[i1]), k2 = __bfloat162float(k[i2]);
    k[i1] = __float2bfloat16(k1 * cv - k2 * sv);
    k[i2] = __float2bfloat16(k2 * cv + k1 * sv);
  }
}

// Causal row softmax in place; reads only k<=q, zeroes (q, S) so PV can tile.
__global__ __launch_bounds__(256) void softmax_kernel(float* __restrict__ scores) {
  __shared__ float buf[Sh];
  __shared__ float sm4[4];
  long r = blockIdx.x;               // b*S + q
  int qi = (int)(r & (Sh - 1));
  float* row = scores + r * (long)Sh;
  int n = qi + 1;
  float m = -3.0e38f;
  for (int o = threadIdx.x; o < n; o += 256) {
    float x = row[o]; buf[o] = x; m = fmaxf(m, x);
  }
  m = block_max(m, sm4);
  float s = 0.f;
  for (int o = threadIdx.x; o < n; o += 256) {
    float e = __expf(buf[o] - m); buf[o] = e; s += e;
  }
  s = block_sum(s, sm4);
  float inv = 1.f / s;
  for (int o = threadIdx.x; o < n; o += 256) row[o] = buf[o] * inv;
  for (int o = n + (int)threadIdx.x; o < Sh; o += 256) row[o] = 0.f;
}

extern "C" void kernel_launch(void* const* d_in, const int* in_sizes, int n_in,
                              void* d_out, int out_size, void* d_ws, size_t ws_size,
                              hipStream_t stream) {
  const float* x       = (const float*)d_in[0];
  const int*   pos     = (const int*)d_in[1];
  const float* ln1_g   = (const float*)d_in[2];
  const float* ln1_b   = (const float*)d_in[3];
  const float* mu_w    = (const float*)d_in[4];
  const float* mu_b    = (const float*)d_in[5];
  const float* proto_w = (const float*)d_in[6];
  const float* gate    = (const float*)d_in[7];
  const float* pt_w    = (const float*)d_in[8];
  const float* pln_g   = (const float*)d_in[9];
  const float* pln_b   = (const float*)d_in[10];
  const float* incoming= (const float*)d_in[11];

  // workspace layout (~268 MB)
  char* w = (char*)d_ws;
  const long BF = 33554432L;  // bytes per bf16 [8192][2048]
  bf16*  ln1    = (bf16*)(w);
  bf16*  q      = (bf16*)(w + BF);
  bf16*  k      = (bf16*)(w + 2 * BF);
  bf16*  v      = (bf16*)(w + 3 * BF);
  bf16*  attn   = (bf16*)(w + 4 * BF);
  float* scores = (float*)(w + 5 * BF);              // f32 [4][2048][2048]; also prc
  float* ps3    = (float*)(w + 5 * BF + 67108864L);  // f32 [2048][2048]
  float* cosT   = (float*)(w + 5 * BF + 67108864L + 16777216L);
  float* sinT   = cosT + (long)Sh * HALF;
  float* ctx    = sinT + (long)Sh * HALF;            // f32 [4][2048]
  float* ctxo   = ctx + Bh * Dh;                     // f32 [4][2048]
  float* routing= ctxo + Bh * Dh;                    // f32 [16][2048] (rows 0-11 qkv, 12-15 o)
  float* gating = routing + 16 * Dh;                 // f32 [16][2048]

  hipMemsetAsync(ctx, 0, 2L * Bh * Dh * sizeof(float), stream);

  rope_table_kernel<<<(Sh * HALF) / 256, 256, 0, stream>>>(cosT, sinT);
  ln1_kernel<<<NROW, 256, 0, stream>>>(x, ln1_g, ln1_b, ln1);
  meanrow_kernel<<<dim3(32, 16), 256, 0, stream>>>(ln1, ctx);
  // prc[n] = incoming[n] @ pt_w[n]^T
  gemm_k<float, float, 0><<<dim3(32, 32, 4), 256, 0, stream>>>(
      incoming, pt_w, scores, Dh, Dh, Dh,
      (long)Dh * Dh, (long)Dh * Dh, (long)Dh * Dh, nullptr, nullptr, nullptr);
  route_kernel<<<dim3(Dh, 4), 256, 0, stream>>>(scores, proto_w, pln_g, pln_b,
                                                gate, ctx, routing, ps3);
  masnorm_kernel<<<12, 256, 0, stream>>>(routing, gating);
  // q/k/v = gating * silu(ln1 @ mu_w[n]^T + mu_b[n])   (q,k,v contiguous, stride NROW*Dh)
  gemm_k<bf16, float, 1><<<dim3(128, 32, 3), 256, 0, stream>>>(
      ln1, mu_w, q, NROW, Dh, Dh,
      0L, (long)Dh * Dh, (long)NROW * Dh, mu_b, gating, nullptr);
  rope_kernel<<<NROW, 256, 0, stream>>>(q, k, pos, cosT, sinT);
  // scores = q @ k^T * inv_sqrt_d (causal blocks only)
  gemm_k<bf16, bf16, 2><<<dim3(32, 32, 4), 256, 0, stream>>>(
      q, k, scores, Sh, Sh, Dh,
      (long)Sh * Dh, (long)Sh * Dh, (long)Sh * Sh, nullptr, nullptr, nullptr);
  softmax_kernel<<<Bh * Sh, 256, 0, stream>>>(scores);
  // attn = probs @ v  (k-range bounded per row tile)
  gemm_k<float, bf16, 3><<<dim3(32, 32, 4), 256, 0, stream>>>(
      scores, v, attn, Sh, Dh, Sh,
      (long)Sh * Sh, (long)Sh * Dh, (long)Sh * Dh, nullptr, nullptr, nullptr);
  meanrow_kernel<<<dim3(32, 16), 256, 0, stream>>>(attn, ctxo);
  route_o_kernel<<<Dh, 256, 0, stream>>>(ps3, ctxo, gate, routing);
  masnorm_kernel<<<4, 256, 0, stream>>>(routing + 12 * Dh, gating + 12 * Dh);
  // out = x + gating_o * silu(attn @ mu_w[3]^T + mu_b[3])
  gemm_k<bf16, float, 4><<<dim3(128, 32, 1), 256, 0, stream>>>(
      attn, mu_w + 3L * Dh * Dh, d_out, NROW, Dh, Dh,
      0L, 0L, 0L, mu_b + 3 * Dh, gating + 12 * Dh, x);
}

// Round 2
// 1102.434 us; speedup vs baseline: 8.3098x; 8.3098x over previous
//
#include <hip/hip_runtime.h>
#include <hip/hip_bf16.h>

#define Dh 2048
#define Bh 4
#define Sh 2048
#define NROW 8192          // B*S
#define HALF 1024
#define INV_SQRT_D 0.022097086912079608f
#define LNEPS 1e-5f

typedef __hip_bfloat16 bf16;
typedef short short8 __attribute__((ext_vector_type(8)));
typedef float f32x4 __attribute__((ext_vector_type(4)));

__device__ inline float cvtf(float v) { return v; }
__device__ inline float cvtf(bf16 v) { return __bfloat162float(v); }

__device__ inline float warp_sum(float x) {
#pragma unroll
  for (int o = 32; o > 0; o >>= 1) x += __shfl_down(x, o);
  return x;
}
__device__ inline float warp_max(float x) {
#pragma unroll
  for (int o = 32; o > 0; o >>= 1) x = fmaxf(x, __shfl_down(x, o));
  return x;
}
__device__ inline float block_sum(float x, float* sm4) {
  x = warp_sum(x);
  int w = threadIdx.x >> 6;
  if ((threadIdx.x & 63) == 0) sm4[w] = x;
  __syncthreads();
  float r = sm4[0] + sm4[1] + sm4[2] + sm4[3];
  __syncthreads();
  return r;
}
__device__ inline float block_max(float x, float* sm4) {
  x = warp_max(x);
  int w = threadIdx.x >> 6;
  if ((threadIdx.x & 63) == 0) sm4[w] = x;
  __syncthreads();
  float r = fmaxf(fmaxf(sm4[0], sm4[1]), fmaxf(sm4[2], sm4[3]));
  __syncthreads();
  return r;
}

// async global->LDS, 16B per lane; LDS dest is wave-uniform base + lane*16
__device__ inline void gload_lds16(const void* g, void* lds) {
  __builtin_amdgcn_global_load_lds(
      (const __attribute__((address_space(1))) unsigned int*)(unsigned long long)g,
      (__attribute__((address_space(3))) unsigned int*)(unsigned long long)lds,
      16, 0, 0);
}

// ---------------------------------------------------------------------------
// MFMA bf16 GEMM: C[M,N] = A[M,K] @ B[N,K]^T. 128x128 tile, BK=32, 4 waves
// (2x2), each wave 64x64 via 4x4 mfma_f32_16x16x32_bf16. m97 structure.
// MODE 0: C f32 = acc                                        (prc)
// MODE 1: C bf16 = silu(acc + e0[z*D+c]) * e1[(z*4+b)*D+c]   (qkv)
// MODE 2: C f32 = acc * INV_SQRT_D, skip blocks above causal diagonal (QK^T)
// MODE 3: C bf16 = acc, K bounded at bm0+128 (causal PV)
// MODE 4: C f32 = e2[r*N+c] + e1[b*D+c] * silu(acc + e0[c])  (o-proj+resid)
// ---------------------------------------------------------------------------
template <int MODE>
__global__ __launch_bounds__(256) void mgemm(
    const bf16* __restrict__ Aall, const bf16* __restrict__ Ball,
    void* __restrict__ Call, int N, int K, int lda, int ldb,
    long sAz, long sBz, long sCz,
    const float* __restrict__ e0, const float* __restrict__ e1,
    const float* __restrict__ e2) {
  int bm0 = blockIdx.x * 128;
  int bn0 = blockIdx.y * 128;
  if (MODE == 2 && bn0 > bm0 + 127) return;  // fully above causal diagonal
  int z = blockIdx.z;
  const bf16* A = Aall + (long)z * sAz;
  const bf16* B = Ball + (long)z * sBz;

  __shared__ bf16 As[128 * 32];  // [row][k] row-major, 64B rows
  __shared__ bf16 Bs[128 * 32];

  int tid = threadIdx.x;
  int l = tid & 63, w = tid >> 6;
  int wr = w >> 1, wc = w & 1;           // wave grid 2x2
  f32x4 acc[4][4] = {};

  int ar = (wr << 6) + (l & 15);         // A fragment row (local)
  int br = (wc << 6) + (l & 15);         // B fragment row (local)
  int ko = (l >> 4) << 4;                // byte offset of k-chunk within row

  int kmax = (MODE == 3) ? (bm0 + 128) : K;

  for (int k0 = 0; k0 < kmax; k0 += 32) {
    // stage 128x32 bf16 tiles (8KB each) via global_load_lds, 2 chunks/wave
#pragma unroll
    for (int qq = 0; qq < 2; ++qq) {
      int chunk = (w << 1) + qq;
      int o = (chunk << 10) + (l << 4);  // byte offset in tile
      int row = o >> 6, colb = o & 63;
      gload_lds16(A + (long)(bm0 + row) * lda + k0 + (colb >> 1),
                  (char*)As + (chunk << 10));
      gload_lds16(B + (long)(bn0 + row) * ldb + k0 + (colb >> 1),
                  (char*)Bs + (chunk << 10));
    }
    __syncthreads();

    short8 af[4], bfr[4];
#pragma unroll
    for (int i = 0; i < 4; ++i) {
      af[i]  = *(const short8*)((const char*)As + (ar + i * 16) * 64 + ko);
      bfr[i] = *(const short8*)((const char*)Bs + (br + i * 16) * 64 + ko);
    }
#pragma unroll
    for (int i = 0; i < 4; ++i)
#pragma unroll
      for (int j = 0; j < 4; ++j)
        acc[i][j] = __builtin_amdgcn_mfma_f32_16x16x32_bf16(af[i], bfr[j],
                                                            acc[i][j], 0, 0, 0);
    __syncthreads();
  }

  // epilogue: C/D mapping col = lane&15, row = (lane>>4)*4 + reg
  int lc = l & 15, lr4 = (l >> 4) << 2;
#pragma unroll
  for (int i = 0; i < 4; ++i) {
    int gr0 = bm0 + (wr << 6) + i * 16 + lr4;
#pragma unroll
    for (int j = 0; j < 4; ++j) {
      int gc = bn0 + (wc << 6) + j * 16 + lc;
#pragma unroll
      for (int qv = 0; qv < 4; ++qv) {
        int gr = gr0 + qv;
        float a = acc[i][j][qv];
        if (MODE == 0) {
          ((float*)Call + (long)z * sCz)[(long)gr * N + gc] = a;
        } else if (MODE == 1) {
          float val = a + e0[z * Dh + gc];
          float sil = val / (1.f + __expf(-val));
          int bb = gr >> 11;
          float g = e1[(z * Bh + bb) * Dh + gc];
          ((bf16*)Call + (long)z * sCz)[(long)gr * N + gc] =
              __float2bfloat16(sil * g);
        } else if (MODE == 2) {
          ((float*)Call + (long)z * sCz)[(long)gr * N + gc] = a * INV_SQRT_D;
        } else if (MODE == 3) {
          ((bf16*)Call + (long)z * sCz)[(long)gr * N + gc] = __float2bfloat16(a);
        } else {
          float val = a + e0[gc];
          float sil = val / (1.f + __expf(-val));
          int bb = gr >> 11;
          ((float*)Call)[(long)gr * N + gc] =
              e2[(long)gr * N + gc] + e1[bb * Dh + gc] * sil;
        }
      }
    }
  }
}

// f32 -> bf16 elementwise, 4 per thread
__global__ __launch_bounds__(256) void cvt_kernel(const float* __restrict__ in,
                                                  bf16* __restrict__ out, long n) {
  long i = ((long)blockIdx.x * 256 + threadIdx.x) * 4;
  if (i >= n) return;
  float4 v = *(const float4*)(in + i);
  out[i + 0] = __float2bfloat16(v.x);
  out[i + 1] = __float2bfloat16(v.y);
  out[i + 2] = __float2bfloat16(v.z);
  out[i + 3] = __float2bfloat16(v.w);
}

// bf16 transpose [4][S][D] -> [4][D][S], 64x64 tiles
__global__ __launch_bounds__(256) void transpose_kernel(const bf16* __restrict__ in,
                                                        bf16* __restrict__ out) {
  __shared__ bf16 t[64][65];
  int b = blockIdx.z;
  int s0 = blockIdx.x * 64, d0 = blockIdx.y * 64;
  const bf16* ib = in + (long)b * Sh * Dh;
  bf16* ob = out + (long)b * Sh * Dh;
  int tx = threadIdx.x & 63, ty = threadIdx.x >> 6;
#pragma unroll
  for (int r = ty; r < 64; r += 4) t[r][tx] = ib[(long)(s0 + r) * Dh + d0 + tx];
  __syncthreads();
#pragma unroll
  for (int r = ty; r < 64; r += 4) ob[(long)(d0 + r) * Sh + s0 + tx] = t[tx][r];
}

// LN over D per (b,s) row of x -> bf16
__global__ __launch_bounds__(256) void ln1_kernel(const float* __restrict__ x,
    const float* __restrict__ g, const float* __restrict__ b, bf16* __restrict__ out) {
  __shared__ float sm4[4];
  long r = blockIdx.x;
  const float* row = x + r * Dh;
  float v[8];
  float s = 0.f, s2 = 0.f;
#pragma unroll
  for (int c = 0; c < 8; ++c) {
    float t = row[threadIdx.x + c * 256];
    v[c] = t; s += t; s2 += t * t;
  }
  s = block_sum(s, sm4);
  s2 = block_sum(s2, sm4);
  float mean = s * (1.f / Dh);
  float rstd = rsqrtf(s2 * (1.f / Dh) - mean * mean + LNEPS);
#pragma unroll
  for (int c = 0; c < 8; ++c) {
    int o = threadIdx.x + c * 256;
    out[r * Dh + o] = __float2bfloat16((v[c] - mean) * rstd * g[o] + b[o]);
  }
}

// outbd[b*D+d] += (1/S) * sum over an s-chunk of in[b,s,d]
__global__ __launch_bounds__(256) void meanrow_kernel(const bf16* __restrict__ in,
                                                      float* __restrict__ outbd) {
  int gid = blockIdx.x * 256 + threadIdx.x;
  int s0 = blockIdx.y * 128;
  long base = ((long)(gid >> 11) * Sh + s0) * Dh + (gid & 2047);
  float s = 0.f;
  for (int t = 0; t < 128; ++t) s += __bfloat162float(in[base + (long)t * Dh]);
  atomicAdd(&outbd[gid], s * (1.f / Sh));
}

// Per (n,i): LN prc row, add proto_w; n<3: dot with ctx -> routing; n==3: store ps3
__global__ __launch_bounds__(256) void route_kernel(
    const float* __restrict__ prc, const float* __restrict__ proto_w,
    const float* __restrict__ pln_g, const float* __restrict__ pln_b,
    const float* __restrict__ gate, const float* __restrict__ ctx,
    float* __restrict__ routing, float* __restrict__ ps3) {
  __shared__ float sm4[4];
  int i = blockIdx.x, n = blockIdx.y;
  long rb = ((long)n * Dh + i) * Dh;
  float v[8];
  float s = 0.f, s2 = 0.f;
#pragma unroll
  for (int c = 0; c < 8; ++c) {
    float t = prc[rb + threadIdx.x + c * 256];
    v[c] = t; s += t; s2 += t * t;
  }
  s = block_sum(s, sm4);
  s2 = block_sum(s2, sm4);
  float mean = s * (1.f / Dh);
  float rstd = rsqrtf(s2 * (1.f / Dh) - mean * mean + LNEPS);
  if (n == 3) {
#pragma unroll
    for (int c = 0; c < 8; ++c) {
      int o = threadIdx.x + c * 256;
      float ps = proto_w[rb + o] + (v[c] - mean) * rstd * pln_g[3 * Dh + o] + pln_b[3 * Dh + o];
      ps3[(long)i * Dh + o] = ps;
    }
  } else {
    float acc[4] = {0.f, 0.f, 0.f, 0.f};
#pragma unroll
    for (int c = 0; c < 8; ++c) {
      int o = threadIdx.x + c * 256;
      float ps = proto_w[rb + o] + (v[c] - mean) * rstd * pln_g[n * Dh + o] + pln_b[n * Dh + o];
#pragma unroll
      for (int b = 0; b < 4; ++b) acc[b] += ps * ctx[b * Dh + o];
    }
    for (int b = 0; b < 4; ++b) {
      float r = block_sum(acc[b], sm4);
      if (threadIdx.x == 0)
        routing[(n * 4 + b) * Dh + i] = r * INV_SQRT_D + gate[n * Dh + i];
    }
  }
}

__global__ __launch_bounds__(256) void route_o_kernel(
    const float* __restrict__ ps3, const float* __restrict__ ctxo,
    const float* __restrict__ gate, float* __restrict__ routing) {
  __shared__ float sm4[4];
  int i = blockIdx.x;
  float acc[4] = {0.f, 0.f, 0.f, 0.f};
#pragma unroll
  for (int c = 0; c < 8; ++c) {
    int o = threadIdx.x + c * 256;
    float p = ps3[(long)i * Dh + o];
#pragma unroll
    for (int b = 0; b < 4; ++b) acc[b] += p * ctxo[b * Dh + o];
  }
  for (int b = 0; b < 4; ++b) {
    float r = block_sum(acc[b], sm4);
    if (threadIdx.x == 0)
      routing[(12 + b) * Dh + i] = r * INV_SQRT_D + gate[3 * Dh + i];
  }
}

__global__ __launch_bounds__(256) void masnorm_kernel(const float* __restrict__ rin,
                                                      float* __restrict__ gout) {
  __shared__ float sm4[4];
  long r = blockIdx.x;
  float m = 0.f;
#pragma unroll
  for (int c = 0; c < 8; ++c)
    m = fmaxf(m, fabsf(rin[r * Dh + threadIdx.x + c * 256]));
  m = block_max(m, sm4);
  float inv = 1.f / (m + 1e-9f);
#pragma unroll
  for (int c = 0; c < 8; ++c) {
    int o = threadIdx.x + c * 256;
    gout[r * Dh + o] = rin[r * Dh + o] * inv;
  }
}

__global__ __launch_bounds__(256) void rope_table_kernel(float* __restrict__ cosT,
                                                         float* __restrict__ sinT) {
  int idx = blockIdx.x * 256 + threadIdx.x;
  int t = idx >> 10, f = idx & 1023;
  float inv_freq = expf(-(float)f * (9.210340371976184f / 1024.f));
  float ang = (float)t * inv_freq;
  cosT[idx] = cosf(ang);
  sinT[idx] = sinf(ang);
}

__global__ __launch_bounds__(256) void rope_kernel(bf16* __restrict__ q, bf16* __restrict__ k,
    const int* __restrict__ pos, const float* __restrict__ cosT,
    const float* __restrict__ sinT) {
  long r = blockIdx.x;
  int s = (int)(r & (Sh - 1));
  int p = pos[s];
#pragma unroll
  for (int c = 0; c < 4; ++c) {
    int t = threadIdx.x + c * 256;
    float cv = cosT[(long)p * HALF + t];
    float sv = sinT[(long)p * HALF + t];
    long i1 = r * Dh + t, i2 = i1 + HALF;
    float q1 = __bfloat162float(q[i1]), q2 = __bfloat162float(q[i2]);
    q[i1] = __float2bfloat16(q1 * cv - q2 * sv);
    q[i2] = __float2bfloat16(q2 * cv + q1 * sv);
    float k1 = __bfloat162float(k[i1]), k2 = __bfloat162float(k[i2]);
    k[i1] = __float2bfloat16(k1 * cv - k2 * sv);
    k[i2] = __float2bfloat16(k2 * cv + k1 * sv);
  }
}

// causal row softmax: read f32 scores (k<=q), write bf16 probs, zero-fill row
__global__ __launch_bounds__(256) void softmax_kernel(const float* __restrict__ scores,
                                                      bf16* __restrict__ probs) {
  __shared__ float buf[Sh];
  __shared__ float sm4[4];
  long r = blockIdx.x;
  int qi = (int)(r & (Sh - 1));
  const float* row = scores + r * (long)Sh;
  bf16* prow = probs + r * (long)Sh;
  int n = qi + 1;
  float m = -3.0e38f;
  for (int o = threadIdx.x; o < n; o += 256) {
    float x = row[o]; buf[o] = x; m = fmaxf(m, x);
  }
  m = block_max(m, sm4);
  float s = 0.f;
  for (int o = threadIdx.x; o < n; o += 256) {
    float e = __expf(buf[o] - m); buf[o] = e; s += e;
  }
  s = block_sum(s, sm4);
  float inv = 1.f / s;
  for (int o = threadIdx.x; o < n; o += 256) prow[o] = __float2bfloat16(buf[o] * inv);
  for (int o = n + (int)threadIdx.x; o < Sh; o += 256) prow[o] = __float2bfloat16(0.f);
}

extern "C" void kernel_launch(void* const* d_in, const int* in_sizes, int n_in,
                              void* d_out, int out_size, void* d_ws, size_t ws_size,
                              hipStream_t stream) {
  const float* x       = (const float*)d_in[0];
  const int*   pos     = (const int*)d_in[1];
  const float* ln1_g   = (const float*)d_in[2];
  const float* ln1_b   = (const float*)d_in[3];
  const float* mu_w    = (const float*)d_in[4];
  const float* mu_b    = (const float*)d_in[5];
  const float* proto_w = (const float*)d_in[6];
  const float* gate    = (const float*)d_in[7];
  const float* pt_w    = (const float*)d_in[8];
  const float* pln_g   = (const float*)d_in[9];
  const float* pln_b   = (const float*)d_in[10];
  const float* incoming= (const float*)d_in[11];

  // workspace layout (~302 MB); scores f32 lives in d_out (dead until o-proj)
  char* w = (char*)d_ws;
  const long BF = 33554432L;  // bytes of one bf16 [8192][2048]
  bf16*  ln1    = (bf16*)(w);
  bf16*  qb     = (bf16*)(w + BF);
  bf16*  kb     = (bf16*)(w + 2 * BF);
  bf16*  vb     = (bf16*)(w + 3 * BF);
  bf16*  attn   = (bf16*)(w + 4 * BF);
  bf16*  mu_wb  = (bf16*)(w + 5 * BF);         // [4][D][D] bf16
  bf16*  ptw_b  = (bf16*)(w + 6 * BF);         // aliased: later vT [4][D][S]
  bf16*  vT     = ptw_b;
  bf16*  inc_b  = (bf16*)(w + 7 * BF);         // aliased: later probs [4][S][S]
  bf16*  probs  = inc_b;
  float* ps3    = (float*)(w + 8 * BF);                 // [2048][2048] f32
  float* cosT   = (float*)(w + 8 * BF + 16777216L);
  float* sinT   = cosT + (long)Sh * HALF;
  float* ctx    = sinT + (long)Sh * HALF;               // [4][2048]
  float* ctxo   = ctx + Bh * Dh;
  float* routing= ctxo + Bh * Dh;                       // [16][2048]
  float* gating = routing + 16 * Dh;                    // [16][2048]
  float* scores = (float*)d_out;                        // f32 [4][2048][2048]

  const long DD4 = 4L * Dh * Dh;

  hipMemsetAsync(ctx, 0, 2L * Bh * Dh * sizeof(float), stream);

  rope_table_kernel<<<(Sh * HALF) / 256, 256, 0, stream>>>(cosT, sinT);
  cvt_kernel<<<DD4 / 1024, 256, 0, stream>>>(mu_w, mu_wb, DD4);
  cvt_kernel<<<DD4 / 1024, 256, 0, stream>>>(incoming, inc_b, DD4);
  cvt_kernel<<<DD4 / 1024, 256, 0, stream>>>(pt_w, ptw_b, DD4);
  ln1_kernel<<<NROW, 256, 0, stream>>>(x, ln1_g, ln1_b, ln1);
  meanrow_kernel<<<dim3(32, 16), 256, 0, stream>>>(ln1, ctx);
  // prc[n] = incoming[n] @ pt_w[n]^T  -> scores (f32, in d_out)
  mgemm<0><<<dim3(16, 16, 4), 256, 0, stream>>>(
      inc_b, ptw_b, scores, Dh, Dh, Dh, Dh,
      (long)Dh * Dh, (long)Dh * Dh, (long)Dh * Dh, nullptr, nullptr, nullptr);
  route_kernel<<<dim3(Dh, 4), 256, 0, stream>>>(scores, proto_w, pln_g, pln_b,
                                                gate, ctx, routing, ps3);
  masnorm_kernel<<<12, 256, 0, stream>>>(routing, gating);
  // q/k/v = gating * silu(ln1 @ mu_w[n]^T + mu_b[n])
  mgemm<1><<<dim3(64, 16, 3), 256, 0, stream>>>(
      ln1, mu_wb, qb, Dh, Dh, Dh, Dh,
      0L, (long)Dh * Dh, (long)NROW * Dh, mu_b, gating, nullptr);
  rope_kernel<<<NROW, 256, 0, stream>>>(qb, kb, pos, cosT, sinT);
  // scores = q @ k^T * inv_sqrt_d (causal blocks only)
  mgemm<2><<<dim3(16, 16, 4), 256, 0, stream>>>(
      qb, kb, scores, Sh, Dh, Dh, Dh,
      (long)Sh * Dh, (long)Sh * Dh, (long)Sh * Sh, nullptr, nullptr, nullptr);
  softmax_kernel<<<Bh * Sh, 256, 0, stream>>>(scores, probs);
  transpose_kernel<<<dim3(32, 32, 4), 256, 0, stream>>>(vb, vT);
  // attn = probs @ v = probs @ vT^T   (K bounded causally per row tile)
  mgemm<3><<<dim3(16, 16, 4), 256, 0, stream>>>(
      probs, vT, attn, Dh, Sh, Sh, Sh,
      (long)Sh * Sh, (long)Dh * Sh, (long)Sh * Dh, nullptr, nullptr, nullptr);
  meanrow_kernel<<<dim3(32, 16), 256, 0, stream>>>(attn, ctxo);
  route_o_kernel<<<Dh, 256, 0, stream>>>(ps3, ctxo, gate, routing);
  masnorm_kernel<<<4, 256, 0, stream>>>(routing + 12 * Dh, gating + 12 * Dh);
  // out = x + gating_o * silu(attn @ mu_w[3]^T + mu_b[3])
  mgemm<4><<<dim3(64, 16, 1), 256, 0, stream>>>(
      attn, mu_wb + 3L * Dh * Dh, d_out, Dh, Dh, Dh, Dh,
      0L, 0L, 0L, mu_b + 3 * Dh, gating + 12 * Dh, x);
}

// Round 3
// 723.549 us; speedup vs baseline: 12.6612x; 1.5236x over previous
//
#include <hip/hip_runtime.h>
#include <hip/hip_bf16.h>

#define Dh 2048
#define Bh 4
#define Sh 2048
#define NROW 8192          // B*S
#define HALF 1024
#define INV_SQRT_D 0.022097086912079608f
#define LNEPS 1e-5f

typedef __hip_bfloat16 bf16;
typedef short short8 __attribute__((ext_vector_type(8)));
typedef float f32x4 __attribute__((ext_vector_type(4)));

__device__ inline float warp_sum(float x) {
#pragma unroll
  for (int o = 32; o > 0; o >>= 1) x += __shfl_down(x, o);
  return x;
}
__device__ inline float warp_max(float x) {
#pragma unroll
  for (int o = 32; o > 0; o >>= 1) x = fmaxf(x, __shfl_down(x, o));
  return x;
}
__device__ inline float block_sum(float x, float* sm4) {
  x = warp_sum(x);
  int w = threadIdx.x >> 6;
  if ((threadIdx.x & 63) == 0) sm4[w] = x;
  __syncthreads();
  float r = sm4[0] + sm4[1] + sm4[2] + sm4[3];
  __syncthreads();
  return r;
}
__device__ inline float block_max(float x, float* sm4) {
  x = warp_max(x);
  int w = threadIdx.x >> 6;
  if ((threadIdx.x & 63) == 0) sm4[w] = x;
  __syncthreads();
  float r = fmaxf(fmaxf(sm4[0], sm4[1]), fmaxf(sm4[2], sm4[3]));
  __syncthreads();
  return r;
}

// async global->LDS, 16B per lane; LDS dest is wave-uniform base + lane*16
__device__ inline void gload_lds16(const void* g, void* lds) {
  __builtin_amdgcn_global_load_lds(
      (const __attribute__((address_space(1))) unsigned int*)(unsigned long long)g,
      (__attribute__((address_space(3))) unsigned int*)(unsigned long long)lds,
      16, 0, 0);
}

// ---------------------------------------------------------------------------
// Phase-pipelined MFMA bf16 GEMM: C[M,N] = A[M,K] @ B[N,K]^T.
// 256x256 tile, BK=32, 8 waves (2Mx4N), per-wave 128x64 output.
// LDS 64KB: 2 buffers x (A 16KB + B 16KB); A/B tiles split in 2 halves of
// 128 rows (8KB, 8 chunks of 1KB, wave w stages chunk w, 1 load/thread).
// Schedule per K-tile t (counted vmcnt, never drained mid-loop):
//   [top: bf16 B-frags (4 reads) held in regs]
//   ph0: A-frag 0,1 reads | stage A(t+1,half0) | 8 MFMA
//   ph1: A-frag 2,3 reads | stage A(t+1,half1) | 8 MFMA
//   s_barrier                                  (protects B region for stages)
//   ph2: A-frag 4,5 reads | stage B(t+2,half0) | 8 MFMA
//   ph3: A-frag 6,7 reads | stage B(t+2,half1) | 8 MFMA
//   vmcnt(2 if t+2<nt else 0); s_barrier       (gates tile t+1's reads)
// Race ledger: A(t+1) stages target buf[(t+1)&1].A, last read iter t-1,
// separated by iter-end barrier. B(t+2) stages target buf[t&1].B, fully
// consumed (reg-held) before mid-barrier. vmcnt+barrier pair makes ALL
// waves' stages for tile t+1 visible before any wave reads them.
// MODE 0: C f32 = acc                                        (prc)
// MODE 1: C bf16 = silu(acc + e0[z*D+c]) * e1[(z*4+b)*D+c]   (qkv)
// MODE 2: C f32 = acc * INV_SQRT_D, skip blocks above diagonal (QK^T)
// MODE 3: C bf16 = acc, K bounded at bm0+256 (causal PV)
// MODE 4: C f32 = e2[r*N+c] + e1[b*D+c] * silu(acc + e0[c])  (o-proj+resid)
// ---------------------------------------------------------------------------
template <int MODE>
__global__ __launch_bounds__(512) void pgemm(
    const bf16* __restrict__ Aall, const bf16* __restrict__ Ball,
    void* __restrict__ Call, int N, int K, int lda, int ldb,
    long sAz, long sBz, long sCz,
    const float* __restrict__ e0, const float* __restrict__ e1,
    const float* __restrict__ e2) {
  const int bm0 = blockIdx.x * 256;
  const int bn0 = blockIdx.y * 256;
  if (MODE == 2 && bn0 > bm0 + 255) return;  // fully above causal diagonal
  const int z = blockIdx.z;
  const bf16* A = Aall + (long)z * sAz;
  const bf16* B = Ball + (long)z * sBz;

  __shared__ __align__(16) char smem[65536];
  const int tid = threadIdx.x;
  const int l = tid & 63, w = tid >> 6;
  const int wr = w >> 2, wc = w & 3;  // wave grid 2x4

  f32x4 acc[8][4] = {};

  const int nt = (MODE == 3) ? ((bm0 + 256) >> 5) : (K >> 5);

  auto stageA = [&](int tt, int half) {
    char* dst = smem + ((tt & 1) << 15) + (half << 13) + (w << 10);
    int row = (half << 7) + (w << 4) + (l >> 2);
    gload_lds16(A + (long)(bm0 + row) * lda + (tt << 5) + ((l & 3) << 3), dst);
  };
  auto stageB = [&](int tt, int half) {
    char* dst = smem + ((tt & 1) << 15) + 16384 + (half << 13) + (w << 10);
    int row = (half << 7) + (w << 4) + (l >> 2);
    gload_lds16(B + (long)(bn0 + row) * ldb + (tt << 5) + ((l & 3) << 3), dst);
  };

  // prologue: tile0 fully + tile1's B halves (steady-state pattern)
  stageA(0, 0); stageA(0, 1); stageB(0, 0); stageB(0, 1);
  if (nt > 1) { stageB(1, 0); stageB(1, 1); }
  if (nt > 1) asm volatile("s_waitcnt vmcnt(2)" ::: "memory");
  else        asm volatile("s_waitcnt vmcnt(0)" ::: "memory");
  __builtin_amdgcn_sched_barrier(0);
  asm volatile("s_barrier" ::: "memory");

#define PH(FR0, FR1, STG)                                                     \
  do {                                                                        \
    short8 xa0 = *(const short8*)(Ab + abyte + FR0 * 1024);                   \
    short8 xa1 = *(const short8*)(Ab + abyte + FR1 * 1024);                   \
    STG;                                                                      \
    __builtin_amdgcn_s_setprio(1);                                            \
    acc[FR0][0] = __builtin_amdgcn_mfma_f32_16x16x32_bf16(xa0, bfv0, acc[FR0][0], 0, 0, 0); \
    acc[FR1][0] = __builtin_amdgcn_mfma_f32_16x16x32_bf16(xa1, bfv0, acc[FR1][0], 0, 0, 0); \
    acc[FR0][1] = __builtin_amdgcn_mfma_f32_16x16x32_bf16(xa0, bfv1, acc[FR0][1], 0, 0, 0); \
    acc[FR1][1] = __builtin_amdgcn_mfma_f32_16x16x32_bf16(xa1, bfv1, acc[FR1][1], 0, 0, 0); \
    acc[FR0][2] = __builtin_amdgcn_mfma_f32_16x16x32_bf16(xa0, bfv2, acc[FR0][2], 0, 0, 0); \
    acc[FR1][2] = __builtin_amdgcn_mfma_f32_16x16x32_bf16(xa1, bfv2, acc[FR1][2], 0, 0, 0); \
    acc[FR0][3] = __builtin_amdgcn_mfma_f32_16x16x32_bf16(xa0, bfv3, acc[FR0][3], 0, 0, 0); \
    acc[FR1][3] = __builtin_amdgcn_mfma_f32_16x16x32_bf16(xa1, bfv3, acc[FR1][3], 0, 0, 0); \
    __builtin_amdgcn_s_setprio(0);                                            \
  } while (0)

  for (int t = 0; t < nt; ++t) {
    const char* Ab = smem + ((t & 1) << 15);
    const char* Bb = Ab + 16384;
    const int abyte = (((wr << 7) + (l & 15)) << 6) + ((l >> 4) << 4);
    const int bbyte = (((wc << 6) + (l & 15)) << 6) + ((l >> 4) << 4);

    short8 bfv0 = *(const short8*)(Bb + bbyte + 0 * 1024);
    short8 bfv1 = *(const short8*)(Bb + bbyte + 1 * 1024);
    short8 bfv2 = *(const short8*)(Bb + bbyte + 2 * 1024);
    short8 bfv3 = *(const short8*)(Bb + bbyte + 3 * 1024);

    PH(0, 1, if (t + 1 < nt) stageA(t + 1, 0));
    PH(2, 3, if (t + 1 < nt) stageA(t + 1, 1));
    asm volatile("s_barrier" ::: "memory");
    PH(4, 5, if (t + 2 < nt) stageB(t + 2, 0));
    PH(6, 7, if (t + 2 < nt) stageB(t + 2, 1));
    if (t < nt - 1) {
      if (t + 2 < nt) asm volatile("s_waitcnt vmcnt(2)" ::: "memory");
      else            asm volatile("s_waitcnt vmcnt(0)" ::: "memory");
      __builtin_amdgcn_sched_barrier(0);
      asm volatile("s_barrier" ::: "memory");
    }
  }
#undef PH

  // epilogue: C/D mapping col = lane&15, row = (lane>>4)*4 + reg
  const int lc = l & 15, lr4 = (l >> 4) << 2;
#pragma unroll
  for (int fr = 0; fr < 8; ++fr) {
    int gr0 = bm0 + (wr << 7) + fr * 16 + lr4;
#pragma unroll
    for (int fc = 0; fc < 4; ++fc) {
      int gc = bn0 + (wc << 6) + fc * 16 + lc;
#pragma unroll
      for (int qv = 0; qv < 4; ++qv) {
        int gr = gr0 + qv;
        float a = acc[fr][fc][qv];
        if (MODE == 0) {
          ((float*)Call + (long)z * sCz)[(long)gr * N + gc] = a;
        } else if (MODE == 1) {
          float val = a + e0[z * Dh + gc];
          float sil = val / (1.f + __expf(-val));
          int bb = gr >> 11;
          float g = e1[(z * Bh + bb) * Dh + gc];
          ((bf16*)Call + (long)z * sCz)[(long)gr * N + gc] =
              __float2bfloat16(sil * g);
        } else if (MODE == 2) {
          ((float*)Call + (long)z * sCz)[(long)gr * N + gc] = a * INV_SQRT_D;
        } else if (MODE == 3) {
          ((bf16*)Call + (long)z * sCz)[(long)gr * N + gc] = __float2bfloat16(a);
        } else {
          float val = a + e0[gc];
          float sil = val / (1.f + __expf(-val));
          int bb = gr >> 11;
          ((float*)Call)[(long)gr * N + gc] =
              e2[(long)gr * N + gc] + e1[bb * Dh + gc] * sil;
        }
      }
    }
  }
}

// f32 -> bf16 elementwise, 4 per thread
__global__ __launch_bounds__(256) void cvt_kernel(const float* __restrict__ in,
                                                  bf16* __restrict__ out, long n) {
  long i = ((long)blockIdx.x * 256 + threadIdx.x) * 4;
  if (i >= n) return;
  float4 v = *(const float4*)(in + i);
  out[i + 0] = __float2bfloat16(v.x);
  out[i + 1] = __float2bfloat16(v.y);
  out[i + 2] = __float2bfloat16(v.z);
  out[i + 3] = __float2bfloat16(v.w);
}

// bf16 transpose [4][S][D] -> [4][D][S], 64x64 tiles
__global__ __launch_bounds__(256) void transpose_kernel(const bf16* __restrict__ in,
                                                        bf16* __restrict__ out) {
  __shared__ bf16 t[64][65];
  int b = blockIdx.z;
  int s0 = blockIdx.x * 64, d0 = blockIdx.y * 64;
  const bf16* ib = in + (long)b * Sh * Dh;
  bf16* ob = out + (long)b * Sh * Dh;
  int tx = threadIdx.x & 63, ty = threadIdx.x >> 6;
#pragma unroll
  for (int r = ty; r < 64; r += 4) t[r][tx] = ib[(long)(s0 + r) * Dh + d0 + tx];
  __syncthreads();
#pragma unroll
  for (int r = ty; r < 64; r += 4) ob[(long)(d0 + r) * Sh + s0 + tx] = t[tx][r];
}

// LN over D per (b,s) row of x -> bf16
__global__ __launch_bounds__(256) void ln1_kernel(const float* __restrict__ x,
    const float* __restrict__ g, const float* __restrict__ b, bf16* __restrict__ out) {
  __shared__ float sm4[4];
  long r = blockIdx.x;
  const float* row = x + r * Dh;
  float v[8];
  float s = 0.f, s2 = 0.f;
#pragma unroll
  for (int c = 0; c < 8; ++c) {
    float t = row[threadIdx.x + c * 256];
    v[c] = t; s += t; s2 += t * t;
  }
  s = block_sum(s, sm4);
  s2 = block_sum(s2, sm4);
  float mean = s * (1.f / Dh);
  float rstd = rsqrtf(s2 * (1.f / Dh) - mean * mean + LNEPS);
#pragma unroll
  for (int c = 0; c < 8; ++c) {
    int o = threadIdx.x + c * 256;
    out[r * Dh + o] = __float2bfloat16((v[c] - mean) * rstd * g[o] + b[o]);
  }
}

// outbd[b*D+d] += (1/S) * sum over an s-chunk of in[b,s,d]
__global__ __launch_bounds__(256) void meanrow_kernel(const bf16* __restrict__ in,
                                                      float* __restrict__ outbd) {
  int gid = blockIdx.x * 256 + threadIdx.x;
  int s0 = blockIdx.y * 128;
  long base = ((long)(gid >> 11) * Sh + s0) * Dh + (gid & 2047);
  float s = 0.f;
  for (int t = 0; t < 128; ++t) s += __bfloat162float(in[base + (long)t * Dh]);
  atomicAdd(&outbd[gid], s * (1.f / Sh));
}

// Per (n,i): LN prc row, add proto_w; n<3: dot with ctx -> routing; n==3: store ps3
__global__ __launch_bounds__(256) void route_kernel(
    const float* __restrict__ prc, const float* __restrict__ proto_w,
    const float* __restrict__ pln_g, const float* __restrict__ pln_b,
    const float* __restrict__ gate, const float* __restrict__ ctx,
    float* __restrict__ routing, float* __restrict__ ps3) {
  __shared__ float sm4[4];
  int i = blockIdx.x, n = blockIdx.y;
  long rb = ((long)n * Dh + i) * Dh;
  float v[8];
  float s = 0.f, s2 = 0.f;
#pragma unroll
  for (int c = 0; c < 8; ++c) {
    float t = prc[rb + threadIdx.x + c * 256];
    v[c] = t; s += t; s2 += t * t;
  }
  s = block_sum(s, sm4);
  s2 = block_sum(s2, sm4);
  float mean = s * (1.f / Dh);
  float rstd = rsqrtf(s2 * (1.f / Dh) - mean * mean + LNEPS);
  if (n == 3) {
#pragma unroll
    for (int c = 0; c < 8; ++c) {
      int o = threadIdx.x + c * 256;
      float ps = proto_w[rb + o] + (v[c] - mean) * rstd * pln_g[3 * Dh + o] + pln_b[3 * Dh + o];
      ps3[(long)i * Dh + o] = ps;
    }
  } else {
    float acc[4] = {0.f, 0.f, 0.f, 0.f};
#pragma unroll
    for (int c = 0; c < 8; ++c) {
      int o = threadIdx.x + c * 256;
      float ps = proto_w[rb + o] + (v[c] - mean) * rstd * pln_g[n * Dh + o] + pln_b[n * Dh + o];
#pragma unroll
      for (int b = 0; b < 4; ++b) acc[b] += ps * ctx[b * Dh + o];
    }
    for (int b = 0; b < 4; ++b) {
      float r = block_sum(acc[b], sm4);
      if (threadIdx.x == 0)
        routing[(n * 4 + b) * Dh + i] = r * INV_SQRT_D + gate[n * Dh + i];
    }
  }
}

__global__ __launch_bounds__(256) void route_o_kernel(
    const float* __restrict__ ps3, const float* __restrict__ ctxo,
    const float* __restrict__ gate, float* __restrict__ routing) {
  __shared__ float sm4[4];
  int i = blockIdx.x;
  float acc[4] = {0.f, 0.f, 0.f, 0.f};
#pragma unroll
  for (int c = 0; c < 8; ++c) {
    int o = threadIdx.x + c * 256;
    float p = ps3[(long)i * Dh + o];
#pragma unroll
    for (int b = 0; b < 4; ++b) acc[b] += p * ctxo[b * Dh + o];
  }
  for (int b = 0; b < 4; ++b) {
    float r = block_sum(acc[b], sm4);
    if (threadIdx.x == 0)
      routing[(12 + b) * Dh + i] = r * INV_SQRT_D + gate[3 * Dh + i];
  }
}

__global__ __launch_bounds__(256) void masnorm_kernel(const float* __restrict__ rin,
                                                      float* __restrict__ gout) {
  __shared__ float sm4[4];
  long r = blockIdx.x;
  float m = 0.f;
#pragma unroll
  for (int c = 0; c < 8; ++c)
    m = fmaxf(m, fabsf(rin[r * Dh + threadIdx.x + c * 256]));
  m = block_max(m, sm4);
  float inv = 1.f / (m + 1e-9f);
#pragma unroll
  for (int c = 0; c < 8; ++c) {
    int o = threadIdx.x + c * 256;
    gout[r * Dh + o] = rin[r * Dh + o] * inv;
  }
}

__global__ __launch_bounds__(256) void rope_table_kernel(float* __restrict__ cosT,
                                                         float* __restrict__ sinT) {
  int idx = blockIdx.x * 256 + threadIdx.x;
  int t = idx >> 10, f = idx & 1023;
  float inv_freq = expf(-(float)f * (9.210340371976184f / 1024.f));
  float ang = (float)t * inv_freq;
  cosT[idx] = cosf(ang);
  sinT[idx] = sinf(ang);
}

__global__ __launch_bounds__(256) void rope_kernel(bf16* __restrict__ q, bf16* __restrict__ k,
    const int* __restrict__ pos, const float* __restrict__ cosT,
    const float* __restrict__ sinT) {
  long r = blockIdx.x;
  int s = (int)(r & (Sh - 1));
  int p = pos[s];
#pragma unroll
  for (int c = 0; c < 4; ++c) {
    int t = threadIdx.x + c * 256;
    float cv = cosT[(long)p * HALF + t];
    float sv = sinT[(long)p * HALF + t];
    long i1 = r * Dh + t, i2 = i1 + HALF;
    float q1 = __bfloat162float(q[i1]), q2 = __bfloat162float(q[i2]);
    q[i1] = __float2bfloat16(q1 * cv - q2 * sv);
    q[i2] = __float2bfloat16(q2 * cv + q1 * sv);
    float k1 = __bfloat162float(k[i1]), k2 = __bfloat162float(k[i2]);
    k[i1] = __float2bfloat16(k1 * cv - k2 * sv);
    k[i2] = __float2bfloat16(k2 * cv + k1 * sv);
  }
}

// causal row softmax: read f32 scores (k<=q), write bf16 probs, zero-fill row
__global__ __launch_bounds__(256) void softmax_kernel(const float* __restrict__ scores,
                                                      bf16* __restrict__ probs) {
  __shared__ float buf[Sh];
  __shared__ float sm4[4];
  long r = blockIdx.x;
  int qi = (int)(r & (Sh - 1));
  const float* row = scores + r * (long)Sh;
  bf16* prow = probs + r * (long)Sh;
  int n = qi + 1;
  float m = -3.0e38f;
  for (int o = threadIdx.x; o < n; o += 256) {
    float x = row[o]; buf[o] = x; m = fmaxf(m, x);
  }
  m = block_max(m, sm4);
  float s = 0.f;
  for (int o = threadIdx.x; o < n; o += 256) {
    float e = __expf(buf[o] - m); buf[o] = e; s += e;
  }
  s = block_sum(s, sm4);
  float inv = 1.f / s;
  for (int o = threadIdx.x; o < n; o += 256) prow[o] = __float2bfloat16(buf[o] * inv);
  for (int o = n + (int)threadIdx.x; o < Sh; o += 256) prow[o] = __float2bfloat16(0.f);
}

extern "C" void kernel_launch(void* const* d_in, const int* in_sizes, int n_in,
                              void* d_out, int out_size, void* d_ws, size_t ws_size,
                              hipStream_t stream) {
  const float* x       = (const float*)d_in[0];
  const int*   pos     = (const int*)d_in[1];
  const float* ln1_g   = (const float*)d_in[2];
  const float* ln1_b   = (const float*)d_in[3];
  const float* mu_w    = (const float*)d_in[4];
  const float* mu_b    = (const float*)d_in[5];
  const float* proto_w = (const float*)d_in[6];
  const float* gate    = (const float*)d_in[7];
  const float* pln_g   = (const float*)d_in[9];
  const float* pln_b   = (const float*)d_in[10];
  const float* pt_w    = (const float*)d_in[8];
  const float* incoming= (const float*)d_in[11];

  // workspace layout (~302 MB); scores f32 lives in d_out (dead until o-proj)
  char* w = (char*)d_ws;
  const long BF = 33554432L;  // bytes of one bf16 [8192][2048]
  bf16*  ln1    = (bf16*)(w);
  bf16*  qb     = (bf16*)(w + BF);
  bf16*  kb     = (bf16*)(w + 2 * BF);
  bf16*  vb     = (bf16*)(w + 3 * BF);
  bf16*  attn   = (bf16*)(w + 4 * BF);
  bf16*  mu_wb  = (bf16*)(w + 5 * BF);         // [4][D][D] bf16
  bf16*  ptw_b  = (bf16*)(w + 6 * BF);         // aliased: later vT [4][D][S]
  bf16*  vT     = ptw_b;
  bf16*  inc_b  = (bf16*)(w + 7 * BF);         // aliased: later probs [4][S][S]
  bf16*  probs  = inc_b;
  float* ps3    = (float*)(w + 8 * BF);                 // [2048][2048] f32
  float* cosT   = (float*)(w + 8 * BF + 16777216L);
  float* sinT   = cosT + (long)Sh * HALF;
  float* ctx    = sinT + (long)Sh * HALF;               // [4][2048]
  float* ctxo   = ctx + Bh * Dh;
  float* routing= ctxo + Bh * Dh;                       // [16][2048]
  float* gating = routing + 16 * Dh;                    // [16][2048]
  float* scores = (float*)d_out;                        // f32 [4][2048][2048]

  const long DD4 = 4L * Dh * Dh;

  hipMemsetAsync(ctx, 0, 2L * Bh * Dh * sizeof(float), stream);

  rope_table_kernel<<<(Sh * HALF) / 256, 256, 0, stream>>>(cosT, sinT);
  cvt_kernel<<<DD4 / 1024, 256, 0, stream>>>(mu_w, mu_wb, DD4);
  cvt_kernel<<<DD4 / 1024, 256, 0, stream>>>(incoming, inc_b, DD4);
  cvt_kernel<<<DD4 / 1024, 256, 0, stream>>>(pt_w, ptw_b, DD4);
  ln1_kernel<<<NROW, 256, 0, stream>>>(x, ln1_g, ln1_b, ln1);
  meanrow_kernel<<<dim3(32, 16), 256, 0, stream>>>(ln1, ctx);
  // prc[n] = incoming[n] @ pt_w[n]^T  -> scores (f32, in d_out)
  pgemm<0><<<dim3(8, 8, 4), 512, 0, stream>>>(
      inc_b, ptw_b, scores, Dh, Dh, Dh, Dh,
      (long)Dh * Dh, (long)Dh * Dh, (long)Dh * Dh, nullptr, nullptr, nullptr);
  route_kernel<<<dim3(Dh, 4), 256, 0, stream>>>(scores, proto_w, pln_g, pln_b,
                                                gate, ctx, routing, ps3);
  masnorm_kernel<<<12, 256, 0, stream>>>(routing, gating);
  // q/k/v = gating * silu(ln1 @ mu_w[n]^T + mu_b[n])
  pgemm<1><<<dim3(32, 8, 3), 512, 0, stream>>>(
      ln1, mu_wb, qb, Dh, Dh, Dh, Dh,
      0L, (long)Dh * Dh, (long)NROW * Dh, mu_b, gating, nullptr);
  rope_kernel<<<NROW, 256, 0, stream>>>(qb, kb, pos, cosT, sinT);
  // scores = q @ k^T * inv_sqrt_d (causal blocks only)
  pgemm<2><<<dim3(8, 8, 4), 512, 0, stream>>>(
      qb, kb, scores, Sh, Dh, Dh, Dh,
      (long)Sh * Dh, (long)Sh * Dh, (long)Sh * Sh, nullptr, nullptr, nullptr);
  softmax_kernel<<<Bh * Sh, 256, 0, stream>>>(scores, probs);
  transpose_kernel<<<dim3(32, 32, 4), 256, 0, stream>>>(vb, vT);
  // attn = probs @ v = probs @ vT^T   (K bounded causally per row tile)
  pgemm<3><<<dim3(8, 8, 4), 512, 0, stream>>>(
      probs, vT, attn, Dh, Sh, Sh, Sh,
      (long)Sh * Sh, (long)Dh * Sh, (long)Sh * Dh, nullptr, nullptr, nullptr);
  meanrow_kernel<<<dim3(32, 16), 256, 0, stream>>>(attn, ctxo);
  route_o_kernel<<<Dh, 256, 0, stream>>>(ps3, ctxo, gate, routing);
  masnorm_kernel<<<4, 256, 0, stream>>>(routing + 12 * Dh, gating + 12 * Dh);
  // out = x + gating_o * silu(attn @ mu_w[3]^T + mu_b[3])
  pgemm<4><<<dim3(32, 8, 1), 512, 0, stream>>>(
      attn, mu_wb + 3L * Dh * Dh, d_out, Dh, Dh, Dh, Dh,
      0L, 0L, 0L, mu_b + 3 * Dh, gating + 12 * Dh, x);
}

// Round 4
// 704.579 us; speedup vs baseline: 13.0021x; 1.0269x over previous
//
#include <hip/hip_runtime.h>
#include <hip/hip_bf16.h>

#define Dh 2048
#define Bh 4
#define Sh 2048
#define NROW 8192          // B*S
#define HALF 1024
#define INV_SQRT_D 0.022097086912079608f
#define LNEPS 1e-5f

typedef __hip_bfloat16 bf16;
typedef short short8 __attribute__((ext_vector_type(8)));
typedef float f32x4 __attribute__((ext_vector_type(4)));

__device__ inline float warp_sum(float x) {
#pragma unroll
  for (int o = 32; o > 0; o >>= 1) x += __shfl_down(x, o);
  return x;
}
__device__ inline float warp_max(float x) {
#pragma unroll
  for (int o = 32; o > 0; o >>= 1) x = fmaxf(x, __shfl_down(x, o));
  return x;
}
__device__ inline float block_sum(float x, float* sm4) {
  x = warp_sum(x);
  int w = threadIdx.x >> 6;
  if ((threadIdx.x & 63) == 0) sm4[w] = x;
  __syncthreads();
  float r = sm4[0] + sm4[1] + sm4[2] + sm4[3];
  __syncthreads();
  return r;
}
__device__ inline float block_max(float x, float* sm4) {
  x = warp_max(x);
  int w = threadIdx.x >> 6;
  if ((threadIdx.x & 63) == 0) sm4[w] = x;
  __syncthreads();
  float r = fmaxf(fmaxf(sm4[0], sm4[1]), fmaxf(sm4[2], sm4[3]));
  __syncthreads();
  return r;
}

// async global->LDS, 16B per lane; LDS dest is wave-uniform base + lane*16
__device__ inline void gload_lds16(const void* g, void* lds) {
  __builtin_amdgcn_global_load_lds(
      (const __attribute__((address_space(1))) unsigned int*)(unsigned long long)g,
      (__attribute__((address_space(3))) unsigned int*)(unsigned long long)lds,
      16, 0, 0);
}

// ---------------------------------------------------------------------------
// Phase-pipelined MFMA bf16 GEMM: C[M,N] = A[M,K] @ B[N,K]^T.
// 256x256 tile, BK=32, 8 waves (2Mx4N), per-wave 128x64 output.
// LDS 64KB: 2 buffers x (A 16KB + B 16KB).
// T2 bank-conflict swizzle (rule #21: both-sides-or-neither):
//   tile row R, 16B-granule slot s: LDS slot s holds global granule
//   g = s ^ ((R>>1)&3). Staging keeps LDS dest LINEAR (global_load_lds
//   constraint) and pre-swizzles the GLOBAL source granule:
//   G = (l&3) ^ ((l>>3)&3)   [since staged R = base16 + (l>>2)].
//   Frag reads use slot (l>>4) ^ ((l>>1)&3)  [since read R = base16 + (l&15)].
//   Result: lanes 0-15 hit addr%128 = {0,64,16,80,...} -> 2-way (free),
//   was 8-way (addr%128 in {0,64} only).
// Schedule per K-tile t (counted vmcnt, never drained mid-loop):
//   ph0: A-frag 0,1 | stage A(t+1,h0) | 8 MFMA   (setprio-wrapped)
//   ph1: A-frag 2,3 | stage A(t+1,h1) | 8 MFMA
//   s_barrier
//   ph2: A-frag 4,5 | stage B(t+2,h0) | 8 MFMA
//   ph3: A-frag 6,7 | stage B(t+2,h1) | 8 MFMA
//   vmcnt(2|0); s_barrier
// MODE 0: C f32 = acc                                        (prc)
// MODE 1: C bf16 = silu(acc + e0[z*D+c]) * e1[(z*4+b)*D+c]   (qkv)
// MODE 2: C f32 = acc * INV_SQRT_D, skip blocks above diagonal (QK^T)
// MODE 3: C bf16 = acc, K bounded at bm0+256 (causal PV)
// MODE 4: C f32 = e2[r*N+c] + e1[b*D+c] * silu(acc + e0[c])  (o-proj+resid)
// ---------------------------------------------------------------------------
template <int MODE>
__global__ __launch_bounds__(512) void pgemm(
    const bf16* __restrict__ Aall, const bf16* __restrict__ Ball,
    void* __restrict__ Call, int N, int K, int lda, int ldb,
    long sAz, long sBz, long sCz,
    const float* __restrict__ e0, const float* __restrict__ e1,
    const float* __restrict__ e2) {
  const int bm0 = blockIdx.x * 256;
  const int bn0 = blockIdx.y * 256;
  if (MODE == 2 && bn0 > bm0 + 255) return;  // fully above causal diagonal
  const int z = blockIdx.z;
  const bf16* A = Aall + (long)z * sAz;
  const bf16* B = Ball + (long)z * sBz;

  __shared__ __align__(16) char smem[65536];
  const int tid = threadIdx.x;
  const int l = tid & 63, w = tid >> 6;
  const int wr = w >> 2, wc = w & 3;  // wave grid 2x4

  f32x4 acc[8][4] = {};

  const int nt = (MODE == 3) ? ((bm0 + 256) >> 5) : (K >> 5);

  // pre-swizzled global source granule for staging (see header comment)
  const int sg = (((l & 3) ^ ((l >> 3) & 3)) << 3);  // element offset, 8 bf16

  auto stageA = [&](int tt, int half) {
    char* dst = smem + ((tt & 1) << 15) + (half << 13) + (w << 10);
    int row = (half << 7) + (w << 4) + (l >> 2);
    gload_lds16(A + (long)(bm0 + row) * lda + (tt << 5) + sg, dst);
  };
  auto stageB = [&](int tt, int half) {
    char* dst = smem + ((tt & 1) << 15) + 16384 + (half << 13) + (w << 10);
    int row = (half << 7) + (w << 4) + (l >> 2);
    gload_lds16(B + (long)(bn0 + row) * ldb + (tt << 5) + sg, dst);
  };

  // prologue: tile0 fully + tile1's B halves (steady-state pattern)
  stageA(0, 0); stageA(0, 1); stageB(0, 0); stageB(0, 1);
  if (nt > 1) { stageB(1, 0); stageB(1, 1); }
  if (nt > 1) asm volatile("s_waitcnt vmcnt(2)" ::: "memory");
  else        asm volatile("s_waitcnt vmcnt(0)" ::: "memory");
  __builtin_amdgcn_sched_barrier(0);
  asm volatile("s_barrier" ::: "memory");

#define PH(FR0, FR1, STG)                                                     \
  do {                                                                        \
    short8 xa0 = *(const short8*)(Ab + abyte + FR0 * 1024);                   \
    short8 xa1 = *(const short8*)(Ab + abyte + FR1 * 1024);                   \
    STG;                                                                      \
    __builtin_amdgcn_s_setprio(1);                                            \
    acc[FR0][0] = __builtin_amdgcn_mfma_f32_16x16x32_bf16(xa0, bfv0, acc[FR0][0], 0, 0, 0); \
    acc[FR1][0] = __builtin_amdgcn_mfma_f32_16x16x32_bf16(xa1, bfv0, acc[FR1][0], 0, 0, 0); \
    acc[FR0][1] = __builtin_amdgcn_mfma_f32_16x16x32_bf16(xa0, bfv1, acc[FR0][1], 0, 0, 0); \
    acc[FR1][1] = __builtin_amdgcn_mfma_f32_16x16x32_bf16(xa1, bfv1, acc[FR1][1], 0, 0, 0); \
    acc[FR0][2] = __builtin_amdgcn_mfma_f32_16x16x32_bf16(xa0, bfv2, acc[FR0][2], 0, 0, 0); \
    acc[FR1][2] = __builtin_amdgcn_mfma_f32_16x16x32_bf16(xa1, bfv2, acc[FR1][2], 0, 0, 0); \
    acc[FR0][3] = __builtin_amdgcn_mfma_f32_16x16x32_bf16(xa0, bfv3, acc[FR0][3], 0, 0, 0); \
    acc[FR1][3] = __builtin_amdgcn_mfma_f32_16x16x32_bf16(xa1, bfv3, acc[FR1][3], 0, 0, 0); \
    __builtin_amdgcn_s_setprio(0);                                            \
  } while (0)

  // swizzled frag-read slot: (l>>4) ^ ((l>>1)&3), constant across frags
  const int rslot = (((l >> 4) ^ ((l >> 1) & 3)) << 4);

  for (int t = 0; t < nt; ++t) {
    const char* Ab = smem + ((t & 1) << 15);
    const char* Bb = Ab + 16384;
    const int abyte = (((wr << 7) + (l & 15)) << 6) + rslot;
    const int bbyte = (((wc << 6) + (l & 15)) << 6) + rslot;

    short8 bfv0 = *(const short8*)(Bb + bbyte + 0 * 1024);
    short8 bfv1 = *(const short8*)(Bb + bbyte + 1 * 1024);
    short8 bfv2 = *(const short8*)(Bb + bbyte + 2 * 1024);
    short8 bfv3 = *(const short8*)(Bb + bbyte + 3 * 1024);

    PH(0, 1, if (t + 1 < nt) stageA(t + 1, 0));
    PH(2, 3, if (t + 1 < nt) stageA(t + 1, 1));
    asm volatile("s_barrier" ::: "memory");
    PH(4, 5, if (t + 2 < nt) stageB(t + 2, 0));
    PH(6, 7, if (t + 2 < nt) stageB(t + 2, 1));
    if (t < nt - 1) {
      if (t + 2 < nt) asm volatile("s_waitcnt vmcnt(2)" ::: "memory");
      else            asm volatile("s_waitcnt vmcnt(0)" ::: "memory");
      __builtin_amdgcn_sched_barrier(0);
      asm volatile("s_barrier" ::: "memory");
    }
  }
#undef PH

  // epilogue: C/D mapping col = lane&15, row = (lane>>4)*4 + reg
  const int lc = l & 15, lr4 = (l >> 4) << 2;
#pragma unroll
  for (int fr = 0; fr < 8; ++fr) {
    int gr0 = bm0 + (wr << 7) + fr * 16 + lr4;
#pragma unroll
    for (int fc = 0; fc < 4; ++fc) {
      int gc = bn0 + (wc << 6) + fc * 16 + lc;
#pragma unroll
      for (int qv = 0; qv < 4; ++qv) {
        int gr = gr0 + qv;
        float a = acc[fr][fc][qv];
        if (MODE == 0) {
          ((float*)Call + (long)z * sCz)[(long)gr * N + gc] = a;
        } else if (MODE == 1) {
          float val = a + e0[z * Dh + gc];
          float sil = val / (1.f + __expf(-val));
          int bb = gr >> 11;
          float g = e1[(z * Bh + bb) * Dh + gc];
          ((bf16*)Call + (long)z * sCz)[(long)gr * N + gc] =
              __float2bfloat16(sil * g);
        } else if (MODE == 2) {
          ((float*)Call + (long)z * sCz)[(long)gr * N + gc] = a * INV_SQRT_D;
        } else if (MODE == 3) {
          ((bf16*)Call + (long)z * sCz)[(long)gr * N + gc] = __float2bfloat16(a);
        } else {
          float val = a + e0[gc];
          float sil = val / (1.f + __expf(-val));
          int bb = gr >> 11;
          ((float*)Call)[(long)gr * N + gc] =
              e2[(long)gr * N + gc] + e1[bb * Dh + gc] * sil;
        }
      }
    }
  }
}

// f32 -> bf16 elementwise for 3 tensors of DD4 elements each (z selects)
__global__ __launch_bounds__(256) void cvt3_kernel(
    const float* __restrict__ s0, const float* __restrict__ s1,
    const float* __restrict__ s2, bf16* __restrict__ o0, bf16* __restrict__ o1,
    bf16* __restrict__ o2, long n) {
  const float* in = (blockIdx.y == 0) ? s0 : (blockIdx.y == 1) ? s1 : s2;
  bf16* out = (blockIdx.y == 0) ? o0 : (blockIdx.y == 1) ? o1 : o2;
  long i = ((long)blockIdx.x * 256 + threadIdx.x) * 4;
  if (i >= n) return;
  float4 v = *(const float4*)(in + i);
  out[i + 0] = __float2bfloat16(v.x);
  out[i + 1] = __float2bfloat16(v.y);
  out[i + 2] = __float2bfloat16(v.z);
  out[i + 3] = __float2bfloat16(v.w);
}

// bf16 transpose [4][S][D] -> [4][D][S], 64x64 tiles
__global__ __launch_bounds__(256) void transpose_kernel(const bf16* __restrict__ in,
                                                        bf16* __restrict__ out) {
  __shared__ bf16 t[64][65];
  int b = blockIdx.z;
  int s0 = blockIdx.x * 64, d0 = blockIdx.y * 64;
  const bf16* ib = in + (long)b * Sh * Dh;
  bf16* ob = out + (long)b * Sh * Dh;
  int tx = threadIdx.x & 63, ty = threadIdx.x >> 6;
#pragma unroll
  for (int r = ty; r < 64; r += 4) t[r][tx] = ib[(long)(s0 + r) * Dh + d0 + tx];
  __syncthreads();
#pragma unroll
  for (int r = ty; r < 64; r += 4) ob[(long)(d0 + r) * Sh + s0 + tx] = t[tx][r];
}

// LN over D per (b,s) row of x -> bf16
__global__ __launch_bounds__(256) void ln1_kernel(const float* __restrict__ x,
    const float* __restrict__ g, const float* __restrict__ b, bf16* __restrict__ out) {
  __shared__ float sm4[4];
  long r = blockIdx.x;
  const float* row = x + r * Dh;
  float v[8];
  float s = 0.f, s2 = 0.f;
#pragma unroll
  for (int c = 0; c < 8; ++c) {
    float t = row[threadIdx.x + c * 256];
    v[c] = t; s += t; s2 += t * t;
  }
  s = block_sum(s, sm4);
  s2 = block_sum(s2, sm4);
  float mean = s * (1.f / Dh);
  float rstd = rsqrtf(s2 * (1.f / Dh) - mean * mean + LNEPS);
#pragma unroll
  for (int c = 0; c < 8; ++c) {
    int o = threadIdx.x + c * 256;
    out[r * Dh + o] = __float2bfloat16((v[c] - mean) * rstd * g[o] + b[o]);
  }
}

// outbd[b*D+d] += (1/S) * sum over an s-chunk of in[b,s,d]
__global__ __launch_bounds__(256) void meanrow_kernel(const bf16* __restrict__ in,
                                                      float* __restrict__ outbd) {
  int gid = blockIdx.x * 256 + threadIdx.x;
  int s0 = blockIdx.y * 128;
  long base = ((long)(gid >> 11) * Sh + s0) * Dh + (gid & 2047);
  float s = 0.f;
  for (int t = 0; t < 128; ++t) s += __bfloat162float(in[base + (long)t * Dh]);
  atomicAdd(&outbd[gid], s * (1.f / Sh));
}

// Per (n,i): LN prc row, add proto_w; n<3: dot with ctx -> routing; n==3: store ps3
__global__ __launch_bounds__(256) void route_kernel(
    const float* __restrict__ prc, const float* __restrict__ proto_w,
    const float* __restrict__ pln_g, const float* __restrict__ pln_b,
    const float* __restrict__ gate, const float* __restrict__ ctx,
    float* __restrict__ routing, float* __restrict__ ps3) {
  __shared__ float sm4[4];
  int i = blockIdx.x, n = blockIdx.y;
  long rb = ((long)n * Dh + i) * Dh;
  float v[8];
  float s = 0.f, s2 = 0.f;
#pragma unroll
  for (int c = 0; c < 8; ++c) {
    float t = prc[rb + threadIdx.x + c * 256];
    v[c] = t; s += t; s2 += t * t;
  }
  s = block_sum(s, sm4);
  s2 = block_sum(s2, sm4);
  float mean = s * (1.f / Dh);
  float rstd = rsqrtf(s2 * (1.f / Dh) - mean * mean + LNEPS);
  if (n == 3) {
#pragma unroll
    for (int c = 0; c < 8; ++c) {
      int o = threadIdx.x + c * 256;
      float ps = proto_w[rb + o] + (v[c] - mean) * rstd * pln_g[3 * Dh + o] + pln_b[3 * Dh + o];
      ps3[(long)i * Dh + o] = ps;
    }
  } else {
    float acc[4] = {0.f, 0.f, 0.f, 0.f};
#pragma unroll
    for (int c = 0; c < 8; ++c) {
      int o = threadIdx.x + c * 256;
      float ps = proto_w[rb + o] + (v[c] - mean) * rstd * pln_g[n * Dh + o] + pln_b[n * Dh + o];
#pragma unroll
      for (int b = 0; b < 4; ++b) acc[b] += ps * ctx[b * Dh + o];
    }
    for (int b = 0; b < 4; ++b) {
      float r = block_sum(acc[b], sm4);
      if (threadIdx.x == 0)
        routing[(n * 4 + b) * Dh + i] = r * INV_SQRT_D + gate[n * Dh + i];
    }
  }
}

__global__ __launch_bounds__(256) void route_o_kernel(
    const float* __restrict__ ps3, const float* __restrict__ ctxo,
    const float* __restrict__ gate, float* __restrict__ routing) {
  __shared__ float sm4[4];
  int i = blockIdx.x;
  float acc[4] = {0.f, 0.f, 0.f, 0.f};
#pragma unroll
  for (int c = 0; c < 8; ++c) {
    int o = threadIdx.x + c * 256;
    float p = ps3[(long)i * Dh + o];
#pragma unroll
    for (int b = 0; b < 4; ++b) acc[b] += p * ctxo[b * Dh + o];
  }
  for (int b = 0; b < 4; ++b) {
    float r = block_sum(acc[b], sm4);
    if (threadIdx.x == 0)
      routing[(12 + b) * Dh + i] = r * INV_SQRT_D + gate[3 * Dh + i];
  }
}

__global__ __launch_bounds__(256) void masnorm_kernel(const float* __restrict__ rin,
                                                      float* __restrict__ gout) {
  __shared__ float sm4[4];
  long r = blockIdx.x;
  float m = 0.f;
#pragma unroll
  for (int c = 0; c < 8; ++c)
    m = fmaxf(m, fabsf(rin[r * Dh + threadIdx.x + c * 256]));
  m = block_max(m, sm4);
  float inv = 1.f / (m + 1e-9f);
#pragma unroll
  for (int c = 0; c < 8; ++c) {
    int o = threadIdx.x + c * 256;
    gout[r * Dh + o] = rin[r * Dh + o] * inv;
  }
}

__global__ __launch_bounds__(256) void rope_table_kernel(float* __restrict__ cosT,
                                                         float* __restrict__ sinT) {
  int idx = blockIdx.x * 256 + threadIdx.x;
  int t = idx >> 10, f = idx & 1023;
  float inv_freq = expf(-(float)f * (9.210340371976184f / 1024.f));
  float ang = (float)t * inv_freq;
  cosT[idx] = cosf(ang);
  sinT[idx] = sinf(ang);
}

__global__ __launch_bounds__(256) void rope_kernel(bf16* __restrict__ q, bf16* __restrict__ k,
    const int* __restrict__ pos, const float* __restrict__ cosT,
    const float* __restrict__ sinT) {
  long r = blockIdx.x;
  int s = (int)(r & (Sh - 1));
  int p = pos[s];
#pragma unroll
  for (int c = 0; c < 4; ++c) {
    int t = threadIdx.x + c * 256;
    float cv = cosT[(long)p * HALF + t];
    float sv = sinT[(long)p * HALF + t];
    long i1 = r * Dh + t, i2 = i1 + HALF;
    float q1 = __bfloat162float(q[i1]), q2 = __bfloat162float(q[i2]);
    q[i1] = __float2bfloat16(q1 * cv - q2 * sv);
    q[i2] = __float2bfloat16(q2 * cv + q1 * sv);
    float k1 = __bfloat162float(k[i1]), k2 = __bfloat162float(k[i2]);
    k[i1] = __float2bfloat16(k1 * cv - k2 * sv);
    k[i2] = __float2bfloat16(k2 * cv + k1 * sv);
  }
}

// causal row softmax: read f32 scores (k<=q), write bf16 probs, zero-fill row
__global__ __launch_bounds__(256) void softmax_kernel(const float* __restrict__ scores,
                                                      bf16* __restrict__ probs) {
  __shared__ float buf[Sh];
  __shared__ float sm4[4];
  long r = blockIdx.x;
  int qi = (int)(r & (Sh - 1));
  const float* row = scores + r * (long)Sh;
  bf16* prow = probs + r * (long)Sh;
  int n = qi + 1;
  float m = -3.0e38f;
  for (int o = threadIdx.x; o < n; o += 256) {
    float x = row[o]; buf[o] = x; m = fmaxf(m, x);
  }
  m = block_max(m, sm4);
  float s = 0.f;
  for (int o = threadIdx.x; o < n; o += 256) {
    float e = __expf(buf[o] - m); buf[o] = e; s += e;
  }
  s = block_sum(s, sm4);
  float inv = 1.f / s;
  for (int o = threadIdx.x; o < n; o += 256) prow[o] = __float2bfloat16(buf[o] * inv);
  for (int o = n + (int)threadIdx.x; o < Sh; o += 256) prow[o] = __float2bfloat16(0.f);
}

extern "C" void kernel_launch(void* const* d_in, const int* in_sizes, int n_in,
                              void* d_out, int out_size, void* d_ws, size_t ws_size,
                              hipStream_t stream) {
  const float* x       = (const float*)d_in[0];
  const int*   pos     = (const int*)d_in[1];
  const float* ln1_g   = (const float*)d_in[2];
  const float* ln1_b   = (const float*)d_in[3];
  const float* mu_w    = (const float*)d_in[4];
  const float* mu_b    = (const float*)d_in[5];
  const float* proto_w = (const float*)d_in[6];
  const float* gate    = (const float*)d_in[7];
  const float* pt_w    = (const float*)d_in[8];
  const float* pln_g   = (const float*)d_in[9];
  const float* pln_b   = (const float*)d_in[10];
  const float* incoming= (const float*)d_in[11];

  // workspace layout (~302 MB); scores f32 lives in d_out (dead until o-proj)
  char* w = (char*)d_ws;
  const long BF = 33554432L;  // bytes of one bf16 [8192][2048]
  bf16*  ln1    = (bf16*)(w);
  bf16*  qb     = (bf16*)(w + BF);
  bf16*  kb     = (bf16*)(w + 2 * BF);
  bf16*  vb     = (bf16*)(w + 3 * BF);
  bf16*  attn   = (bf16*)(w + 4 * BF);
  bf16*  mu_wb  = (bf16*)(w + 5 * BF);         // [4][D][D] bf16
  bf16*  ptw_b  = (bf16*)(w + 6 * BF);         // aliased: later vT [4][D][S]
  bf16*  vT     = ptw_b;
  bf16*  inc_b  = (bf16*)(w + 7 * BF);         // aliased: later probs [4][S][S]
  bf16*  probs  = inc_b;
  float* ps3    = (float*)(w + 8 * BF);                 // [2048][2048] f32
  float* cosT   = (float*)(w + 8 * BF + 16777216L);
  float* sinT   = cosT + (long)Sh * HALF;
  float* ctx    = sinT + (long)Sh * HALF;               // [4][2048]
  float* ctxo   = ctx + Bh * Dh;
  float* routing= ctxo + Bh * Dh;                       // [16][2048]
  float* gating = routing + 16 * Dh;                    // [16][2048]
  float* scores = (float*)d_out;                        // f32 [4][2048][2048]

  const long DD4 = 4L * Dh * Dh;

  hipMemsetAsync(ctx, 0, 2L * Bh * Dh * sizeof(float), stream);

  rope_table_kernel<<<(Sh * HALF) / 256, 256, 0, stream>>>(cosT, sinT);
  cvt3_kernel<<<dim3(DD4 / 1024, 3), 256, 0, stream>>>(
      mu_w, incoming, pt_w, mu_wb, inc_b, ptw_b, DD4);
  ln1_kernel<<<NROW, 256, 0, stream>>>(x, ln1_g, ln1_b, ln1);
  meanrow_kernel<<<dim3(32, 16), 256, 0, stream>>>(ln1, ctx);
  // prc[n] = incoming[n] @ pt_w[n]^T  -> scores (f32, in d_out)
  pgemm<0><<<dim3(8, 8, 4), 512, 0, stream>>>(
      inc_b, ptw_b, scores, Dh, Dh, Dh, Dh,
      (long)Dh * Dh, (long)Dh * Dh, (long)Dh * Dh, nullptr, nullptr, nullptr);
  route_kernel<<<dim3(Dh, 4), 256, 0, stream>>>(scores, proto_w, pln_g, pln_b,
                                                gate, ctx, routing, ps3);
  masnorm_kernel<<<12, 256, 0, stream>>>(routing, gating);
  // q/k/v = gating * silu(ln1 @ mu_w[n]^T + mu_b[n])
  pgemm<1><<<dim3(32, 8, 3), 512, 0, stream>>>(
      ln1, mu_wb, qb, Dh, Dh, Dh, Dh,
      0L, (long)Dh * Dh, (long)NROW * Dh, mu_b, gating, nullptr);
  rope_kernel<<<NROW, 256, 0, stream>>>(qb, kb, pos, cosT, sinT);
  // scores = q @ k^T * inv_sqrt_d (causal blocks only)
  pgemm<2><<<dim3(8, 8, 4), 512, 0, stream>>>(
      qb, kb, scores, Sh, Dh, Dh, Dh,
      (long)Sh * Dh, (long)Sh * Dh, (long)Sh * Sh, nullptr, nullptr, nullptr);
  softmax_kernel<<<Bh * Sh, 256, 0, stream>>>(scores, probs);
  transpose_kernel<<<dim3(32, 32, 4), 256, 0, stream>>>(vb, vT);
  // attn = probs @ v = probs @ vT^T   (K bounded causally per row tile)
  pgemm<3><<<dim3(8, 8, 4), 512, 0, stream>>>(
      probs, vT, attn, Dh, Sh, Sh, Sh,
      (long)Sh * Sh, (long)Dh * Sh, (long)Sh * Dh, nullptr, nullptr, nullptr);
  meanrow_kernel<<<dim3(32, 16), 256, 0, stream>>>(attn, ctxo);
  route_o_kernel<<<Dh, 256, 0, stream>>>(ps3, ctxo, gate, routing);
  masnorm_kernel<<<4, 256, 0, stream>>>(routing + 12 * Dh, gating + 12 * Dh);
  // out = x + gating_o * silu(attn @ mu_w[3]^T + mu_b[3])
  pgemm<4><<<dim3(32, 8, 1), 512, 0, stream>>>(
      attn, mu_wb + 3L * Dh * Dh, d_out, Dh, Dh, Dh, Dh,
      0L, 0L, 0L, mu_b + 3 * Dh, gating + 12 * Dh, x);
}